// Round 14
// baseline (109.702 us; speedup 1.0000x reference)
//
#include <hip/hip_runtime.h>
#include <stdint.h>

typedef short bf16x8 __attribute__((ext_vector_type(8)));
typedef float f32x4 __attribute__((ext_vector_type(4)));
typedef unsigned short ushort_t;
typedef ushort_t ushort8 __attribute__((ext_vector_type(8)));

#define TOKENS 131072
#define DMODEL 128
#define DIN 160
#define DHID 512
#define NEXP 8
#define BEH 32
#define CAP 24576
#define MT 32
#define TILES (CAP / MT)   /* 768 */

// workspace layout (bytes)
#define OFF_COUNTS 0
#define OFF_LISTS  1024
#define OFF_WIP    (OFF_LISTS + NEXP*CAP*4)
#define OFF_WOP    (OFF_WIP + 8*32*5*64*8*2)

#define SCATTER_BLOCKS (TOKENS / 256)                /* 512 */
#define NWI (8*32*5*64)                              /* 81920 */
#define NWO (8*8*16*64)                              /* 65536 */
#define PACK_BLOCKS ((NWI + NWO + 255) / 256)        /* 576 */

#define WI_STEP_SHORTS 5120   /* 10 KB per step buffer: Wi only (Wo via regs) */

typedef const __attribute__((address_space(1))) uint32_t* gu32p;
typedef __attribute__((address_space(3))) uint32_t* lu32p;

__device__ __forceinline__ ushort_t f2b(float f) {
    union { float f; uint32_t u; } x; x.f = f;
    uint32_t r = x.u + 0x7FFF + ((x.u >> 16) & 1);   // RNE
    return (ushort_t)(r >> 16);
}

// pack two f32 -> two bf16 (round-half-up)
__device__ __forceinline__ uint32_t pk2(float lo, float hi) {
    uint32_t a = __float_as_uint(lo) + 0x8000u;
    uint32_t b = __float_as_uint(hi) + 0x8000u;
    return (a >> 16) | (b & 0xFFFF0000u);
}

// ---------------- Phase A+B fused: scatter tokens + pack weights ----------------
// Hidden dimension PERMUTED (R8 win) so GEMM1's per-lane C fragment IS GEMM2's
// per-lane A fragment (no cross-lane shuffles). GEMM1 tile u (of step s),
// tile-row i computes hidden unit H = s*32 + (i>>2)*8 + u*4 + (i&3).
__global__ __launch_bounds__(256) void prep_kernel(
    const int* __restrict__ pos, int* __restrict__ counts, int* __restrict__ lists,
    const float* __restrict__ Wi, const float* __restrict__ Wo,
    ushort_t* __restrict__ wiP, ushort_t* __restrict__ woP)
{
    __shared__ int lcnt[NEXP];
    __shared__ int lbase[NEXP];
    int tid = threadIdx.x;
    if (blockIdx.x < SCATTER_BLOCKS) {
        if (tid < NEXP) lcnt[tid] = 0;
        __syncthreads();
        int t = blockIdx.x * 256 + tid;
        int e = pos[t];
        int slot = atomicAdd(&lcnt[e], 1);
        __syncthreads();
        if (tid < NEXP) lbase[tid] = atomicAdd(&counts[tid], lcnt[tid]);
        __syncthreads();
        int p = lbase[e] + slot;
        if (p < CAP) lists[e * CAP + p] = t;
        return;
    }
    int idx = (blockIdx.x - SCATTER_BLOCKS) * 256 + tid;
    if (idx < NWI) {
        int L = idx & 63; int r = idx >> 6;
        int s = r % 5; r /= 5;
        int t1 = r & 31; int e = r >> 5;
        // permuted hidden index: tile t1 = 2*sI + u, row i = L&15
        int i = L & 15;
        int u = t1 & 1, sI = t1 >> 1;
        int n = sI * 32 + (i >> 2) * 8 + u * 4 + (i & 3);
        int kb = s * 32 + ((L >> 4) & 3) * 8;
        ushort8 o;
        #pragma unroll
        for (int j = 0; j < 8; ++j)
            o[j] = f2b(Wi[((size_t)e * DIN + kb + j) * DHID + n]);
        *(ushort8*)(wiP + (size_t)idx * 8) = o;
    } else {
        int i2 = idx - NWI;
        if (i2 >= NWO) return;
        int L = i2 & 63; int r = i2 >> 6;
        int ks = r & 15; r >>= 4;
        int t2 = r & 7; int e = r >> 3;
        int n = t2 * 16 + (L & 15);
        int kb = ks * 32 + ((L >> 4) & 3) * 8;
        ushort8 o;
        #pragma unroll
        for (int j = 0; j < 8; ++j)
            o[j] = f2b(Wo[((size_t)e * DHID + kb + j) * DMODEL + n]);
        *(ushort8*)(woP + (size_t)i2 * 8) = o;
    }
}

// async-stage one K-step of Wi (10 KB = 640 granules of 16B) with ONE wave:
// exactly 10 global_load_lds per lane, NO conditionals (vmcnt count must be
// wave-exact for the drain-free pipeline).
__device__ __forceinline__ void stage_wi(
    const ushort_t* __restrict__ wiPe, ushort_t* dstBuf, int step, int lane)
{
    #pragma unroll
    for (int it = 0; it < 10; ++it) {
        int g = it * 64 + lane;
        const ushort_t* src = wiPe + (size_t)step * 5120 + (size_t)g * 8;
        __builtin_amdgcn_global_load_lds((gu32p)(const void*)src,
                                         (lu32p)(void*)(dstBuf + g * 8), 16, 0, 0);
    }
}

// x = concat(hidden[t], emb[bi]); 8 consecutive floats at col c0 (8-aligned)
__device__ __forceinline__ bf16x8 load_x8(const float* __restrict__ hidden,
                                          const float* __restrict__ emb,
                                          int t, int bi, int c0) {
    if (t < 0) return (bf16x8)0;
    const float* src = (c0 < DMODEL) ? (hidden + (size_t)t * DMODEL + c0)
                                     : (emb + (size_t)bi * BEH + (c0 - DMODEL));
    f32x4 p0 = *(const f32x4*)src;
    f32x4 p1 = *(const f32x4*)(src + 4);
    uint32_t d0 = pk2(p0[0], p0[1]), d1 = pk2(p0[2], p0[3]);
    uint32_t d2 = pk2(p1[0], p1[1]), d3 = pk2(p1[2], p1[3]);
    return __builtin_bit_cast(bf16x8, (uint4){d0, d1, d2, d3});
}

// ---------------- Phase C: per-expert fused MLP (drain-free pipeline) ----------------
// SINGLE-WAVE blocks (32 tokens, wave owns 2 token-tiles, R8 shuffle-free
// dataflow). The session invariant: block-step wall ~4000 cy in EVERY
// barriered variant while content is only ~600-1500 cy -- the fixed cost is
// the __syncthreads drain protocol (vmcnt(0) + cold refill each step).
// Single-wave blocks have no cross-wave staging race, so counted vmcnt is
// exact: per step issue wof(step+1) [8 loads, reg ping-pong] then
// stage(step+1) [10 global_load_lds], then s_waitcnt vmcnt(18) -- retires
// last iteration's {wof, stage} while the 18 new loads stay in flight.
// NO vmcnt(0), NO barrier anywhere in the main loop.
// Counts are exact: per-iteration VMEM issue is unconditional (8+10);
// prologue-gather count variance only strengthens the wait (oldest-first).
__global__ __launch_bounds__(64, 2) void expert_gemm(
    const float* __restrict__ hidden, const int* __restrict__ bindex,
    const int* __restrict__ lists, const int* __restrict__ counts,
    const ushort_t* __restrict__ wiP, const ushort_t* __restrict__ woP,
    const float* __restrict__ emb, float* __restrict__ out)
{
    int e = blockIdx.y;
    int tile = blockIdx.x;
    int count = counts[e]; if (count > CAP) count = CAP;
    int base = tile * MT;
    if (base >= count) return;
    int mvalid = count - base; if (mvalid > MT) mvalid = MT;

    __shared__ ushort_t wbuf[2][WI_STEP_SHORTS];   // 20 KB

    int lane = threadIdx.x & 63;
    int l15 = lane & 15;
    int quad = lane >> 4;

    const int* listE = lists + (size_t)e * CAP + base;
    const ushort_t* wiPe = wiP + (size_t)e * 32 * 5 * 64 * 8;
    const ushort_t* woPe = woP + (size_t)e * 8 * 16 * 64 * 8;   // [n 8][ks 16][64][8]

    // ---- prologue: gather x (oldest VMEM), then wof(0), then stage(0)
    bf16x8 xf[2][5];
    int tok[2], bi[2];
    #pragma unroll
    for (int tt = 0; tt < 2; ++tt) {
        int row = tt * 16 + l15;
        tok[tt] = -1; bi[tt] = 0;
        if (row < mvalid) { tok[tt] = listE[row]; bi[tt] = bindex[tok[tt]]; }
    }
    #pragma unroll
    for (int s = 0; s < 5; ++s) {
        int c0 = s * 32 + quad * 8;
        xf[0][s] = load_x8(hidden, emb, tok[0], bi[0], c0);
        xf[1][s] = load_x8(hidden, emb, tok[1], bi[1], c0);
    }

    bf16x8 wofA[8], wofB[8];
    #pragma unroll
    for (int n = 0; n < 8; ++n)
        wofA[n] = *(const bf16x8*)&woPe[((size_t)(n * 16 + 0) * 64 + lane) * 8];

    stage_wi(wiPe, wbuf[0], 0, lane);

    f32x4 yacc[2][8] = {};

    #pragma unroll 1   // iteration mixing would corrupt the vmcnt arithmetic
    for (int step = 0; step < 16; ++step) {
        int cur = step & 1;
        bool even = (cur == 0);

        if (step + 1 < 16) {
            // prefetch next step's Wo frags into the other register bank
            const ushort_t* woN = woPe + (size_t)(step + 1) * 512;
            #pragma unroll
            for (int n = 0; n < 8; ++n) {
                bf16x8 v = *(const bf16x8*)&woN[(size_t)n * 8192 + lane * 8];
                if (even) wofB[n] = v; else wofA[n] = v;
            }
            // stage next step's Wi into the other LDS buffer
            stage_wi(wiPe, wbuf[cur ^ 1], step + 1, lane);
            // retire last iteration's {wof(step), stage(step)}; keep the 18
            // just-issued loads in flight across this step's compute
            asm volatile("s_waitcnt vmcnt(18)" ::: "memory");
        } else {
            asm volatile("s_waitcnt vmcnt(0)" ::: "memory");
        }
        __builtin_amdgcn_sched_barrier(0);

        const ushort_t* wiS = wbuf[cur];        // [2 tiles][5 s][64][8]

        // GEMM1^T: hT[32 hid x 32 tok] = Wi-tiles @ x  (hid order permuted)
        f32x4 hacc[2][2] = {};
        #pragma unroll
        for (int s = 0; s < 5; ++s) {
            bf16x8 a0 = *(const bf16x8*)&wiS[(0 * 5 + s) * 512 + lane * 8];
            bf16x8 a1 = *(const bf16x8*)&wiS[(1 * 5 + s) * 512 + lane * 8];
            #pragma unroll
            for (int tt = 0; tt < 2; ++tt) {
                hacc[0][tt] = __builtin_amdgcn_mfma_f32_16x16x32_bf16(a0, xf[tt][s], hacc[0][tt], 0, 0, 0);
                hacc[1][tt] = __builtin_amdgcn_mfma_f32_16x16x32_bf16(a1, xf[tt][s], hacc[1][tt], 0, 0, 0);
            }
        }
        // relu + pack: lane-local A-frag build (hidden-permutation => no shuffles)
        bf16x8 afrag[2];
        #pragma unroll
        for (int tt = 0; tt < 2; ++tt) {
            f32x4 h0 = hacc[0][tt], h1 = hacc[1][tt];
            #pragma unroll
            for (int r = 0; r < 4; ++r) {
                h0[r] = h0[r] > 0.f ? h0[r] : 0.f;
                h1[r] = h1[r] > 0.f ? h1[r] : 0.f;
            }
            uint4 dv = { pk2(h0[0], h0[1]), pk2(h0[2], h0[3]),
                         pk2(h1[0], h1[1]), pk2(h1[2], h1[3]) };
            afrag[tt] = __builtin_bit_cast(bf16x8, dv);
        }
        // GEMM2: B-frags from the CURRENT register bank (loaded last iter)
        #pragma unroll
        for (int n = 0; n < 8; ++n) {
            bf16x8 b = even ? wofA[n] : wofB[n];
            yacc[0][n] = __builtin_amdgcn_mfma_f32_16x16x32_bf16(afrag[0], b, yacc[0][n], 0, 0, 0);
            yacc[1][n] = __builtin_amdgcn_mfma_f32_16x16x32_bf16(afrag[1], b, yacc[1][n], 0, 0, 0);
        }
    }

    // epilogue: yacc C-layout -> out[token][dmodel]
    #pragma unroll
    for (int tt = 0; tt < 2; ++tt)
        #pragma unroll
        for (int r = 0; r < 4; ++r) {
            int row = tt * 16 + quad * 4 + r;
            if (row < mvalid) {
                int t = listE[row];
                float* dst = out + (size_t)t * DMODEL + l15;
                #pragma unroll
                for (int n = 0; n < 8; ++n)
                    dst[n * 16] = yacc[tt][n][r];
            }
        }
}

extern "C" void kernel_launch(void* const* d_in, const int* in_sizes, int n_in,
                              void* d_out, int out_size, void* d_ws, size_t ws_size,
                              hipStream_t stream) {
    const float* hidden = (const float*)d_in[0];
    const int*   pos    = (const int*)d_in[1];
    const int*   beh    = (const int*)d_in[2];
    const float* Wi     = (const float*)d_in[3];
    const float* Wo     = (const float*)d_in[4];
    const float* emb    = (const float*)d_in[5];

    char* ws = (char*)d_ws;
    int* counts   = (int*)(ws + OFF_COUNTS);
    int* lists    = (int*)(ws + OFF_LISTS);
    ushort_t* wiP = (ushort_t*)(ws + OFF_WIP);
    ushort_t* woP = (ushort_t*)(ws + OFF_WOP);

    hipMemsetAsync(counts, 0, NEXP * sizeof(int), stream);
    prep_kernel<<<SCATTER_BLOCKS + PACK_BLOCKS, 256, 0, stream>>>(pos, counts, lists, Wi, Wo, wiP, woP);
    expert_gemm<<<dim3(TILES, NEXP), 64, 0, stream>>>(
        hidden, beh, lists, counts, wiP, woP, emb, (float*)d_out);
}

// Round 15
// 76.491 us; speedup vs baseline: 1.4342x; 1.4342x over previous
//
#include <hip/hip_runtime.h>
#include <stdint.h>

typedef short bf16x8 __attribute__((ext_vector_type(8)));
typedef float f32x4 __attribute__((ext_vector_type(4)));
typedef unsigned short ushort_t;
typedef ushort_t ushort8 __attribute__((ext_vector_type(8)));

#define TOKENS 131072
#define DMODEL 128
#define DIN 160
#define DHID 512
#define NEXP 8
#define BEH 32
#define CAP 24576
#define MT 64

// flat compact grid: sum ceil(count_e/MT) <= TOKENS/MT + NEXP = 2056
#define GEMM_BLOCKS (TOKENS / MT + NEXP)   /* 2056 */

// workspace layout (bytes)
#define OFF_COUNTS 0
#define OFF_LISTS  1024
#define OFF_WIP    (OFF_LISTS + NEXP*CAP*4)
#define OFF_WOP    (OFF_WIP + 8*32*5*64*8*2)

#define SCATTER_BLOCKS (TOKENS / 256)                /* 512 */
#define NWI (8*32*5*64)                              /* 81920 */
#define NWO (8*8*16*64)                              /* 65536 */
#define PACK_BLOCKS ((NWI + NWO + 255) / 256)        /* 576 */

#define STEP_SHORTS 9216   /* 18 KB per step buffer: 5120 wi + 4096 wo (shorts) */

typedef const __attribute__((address_space(1))) uint32_t* gu32p;
typedef __attribute__((address_space(3))) uint32_t* lu32p;

__device__ __forceinline__ ushort_t f2b(float f) {
    union { float f; uint32_t u; } x; x.f = f;
    uint32_t r = x.u + 0x7FFF + ((x.u >> 16) & 1);   // RNE
    return (ushort_t)(r >> 16);
}

// pack two f32 -> two bf16 (round-half-up)
__device__ __forceinline__ uint32_t pk2(float lo, float hi) {
    uint32_t a = __float_as_uint(lo) + 0x8000u;
    uint32_t b = __float_as_uint(hi) + 0x8000u;
    return (a >> 16) | (b & 0xFFFF0000u);
}

// ---------------- Phase A+B fused: scatter tokens + pack weights ----------------
// Hidden dimension PERMUTED (R8 win) so GEMM1's per-lane C fragment IS GEMM2's
// per-lane A fragment (no cross-lane shuffles). GEMM1 tile u (of step s),
// tile-row i computes hidden unit H = s*32 + (i>>2)*8 + u*4 + (i&3).
__global__ __launch_bounds__(256) void prep_kernel(
    const int* __restrict__ pos, int* __restrict__ counts, int* __restrict__ lists,
    const float* __restrict__ Wi, const float* __restrict__ Wo,
    ushort_t* __restrict__ wiP, ushort_t* __restrict__ woP)
{
    __shared__ int lcnt[NEXP];
    __shared__ int lbase[NEXP];
    int tid = threadIdx.x;
    if (blockIdx.x < SCATTER_BLOCKS) {
        if (tid < NEXP) lcnt[tid] = 0;
        __syncthreads();
        int t = blockIdx.x * 256 + tid;
        int e = pos[t];
        int slot = atomicAdd(&lcnt[e], 1);
        __syncthreads();
        if (tid < NEXP) lbase[tid] = atomicAdd(&counts[tid], lcnt[tid]);
        __syncthreads();
        int p = lbase[e] + slot;
        if (p < CAP) lists[e * CAP + p] = t;
        return;
    }
    int idx = (blockIdx.x - SCATTER_BLOCKS) * 256 + tid;
    if (idx < NWI) {
        int L = idx & 63; int r = idx >> 6;
        int s = r % 5; r /= 5;
        int t1 = r & 31; int e = r >> 5;
        // permuted hidden index: tile t1 = 2*sI + u, row i = L&15
        int i = L & 15;
        int u = t1 & 1, sI = t1 >> 1;
        int n = sI * 32 + (i >> 2) * 8 + u * 4 + (i & 3);
        int kb = s * 32 + ((L >> 4) & 3) * 8;
        ushort8 o;
        #pragma unroll
        for (int j = 0; j < 8; ++j)
            o[j] = f2b(Wi[((size_t)e * DIN + kb + j) * DHID + n]);
        *(ushort8*)(wiP + (size_t)idx * 8) = o;
    } else {
        int i2 = idx - NWI;
        if (i2 >= NWO) return;
        int L = i2 & 63; int r = i2 >> 6;
        int ks = r & 15; r >>= 4;
        int t2 = r & 7; int e = r >> 3;
        int n = t2 * 16 + (L & 15);
        int kb = ks * 32 + ((L >> 4) & 3) * 8;
        ushort8 o;
        #pragma unroll
        for (int j = 0; j < 8; ++j)
            o[j] = f2b(Wo[((size_t)e * DHID + kb + j) * DMODEL + n]);
        *(ushort8*)(woP + (size_t)i2 * 8) = o;
    }
}

// async-stage one K-step's weight fragments (18 KB) into dstBuf.
// granules g: [0,640) = Wi (10 KB contiguous at step*10KB); [640,1152) = Wo,
// 8 regions of 1 KB at ((n*16+step)*64)*16 bytes. All branches wave-uniform.
__device__ __forceinline__ void stage_step(
    const ushort_t* __restrict__ wiPe, const ushort_t* __restrict__ woPe,
    ushort_t* dstBuf, int step, int tid)
{
    #pragma unroll
    for (int it = 0; it < 5; ++it) {
        int g = it * 256 + tid;
        if (it == 4 && tid >= 128) break;          // waves 2,3 skip (uniform)
        const ushort_t* src;
        if (g < 640) {
            src = wiPe + (size_t)step * 5120 + (size_t)g * 8;
        } else {
            int g2 = g - 640;
            src = woPe + ((size_t)(((g2 >> 6) * 16 + step) * 64 + (g2 & 63))) * 8;
        }
        __builtin_amdgcn_global_load_lds((gu32p)(const void*)src,
                                         (lu32p)(void*)(dstBuf + g * 8), 16, 0, 0);
    }
}

// x = concat(hidden[t], emb[bi]); 8 consecutive floats at col c0 (8-aligned)
__device__ __forceinline__ bf16x8 load_x8(const float* __restrict__ hidden,
                                          const float* __restrict__ emb,
                                          int t, int bi, int c0) {
    if (t < 0) return (bf16x8)0;
    const float* src = (c0 < DMODEL) ? (hidden + (size_t)t * DMODEL + c0)
                                     : (emb + (size_t)bi * BEH + (c0 - DMODEL));
    f32x4 p0 = *(const f32x4*)src;
    f32x4 p1 = *(const f32x4*)(src + 4);
    uint32_t d0 = pk2(p0[0], p0[1]), d1 = pk2(p0[2], p0[3]);
    uint32_t d2 = pk2(p1[0], p1[1]), d3 = pk2(p1[2], p1[3]);
    return __builtin_bit_cast(bf16x8, (uint4){d0, d1, d2, d3});
}

// ---------------- Phase C: per-expert fused MLP ----------------
// The 77.2us champion (64-token blocks, 4 light 1-tile waves, shuffle-free,
// ~88 unified regs = 16-wave bucket) with a COMPACT FLAT GRID: instead of
// dim3(CAP/MT=384, 8) with ~1024 empty blocks interleaved in 128-block runs,
// launch 2056 1-D blocks and derive (expert, tile) from counts[] via an
// 8-iteration prefix scan. Every dispatched block is real work, contiguous
// and balanced -- targets the measured 33% occupancy vs the 50% (16-wave)
// cap that LDS/regs allow.
__global__ __launch_bounds__(256, 4) void expert_gemm(
    const float* __restrict__ hidden, const int* __restrict__ bindex,
    const int* __restrict__ lists, const int* __restrict__ counts,
    const ushort_t* __restrict__ wiP, const ushort_t* __restrict__ woP,
    const float* __restrict__ emb, float* __restrict__ out)
{
    // ---- flat bid -> (e, tile) via prefix scan over tile counts
    int bid = blockIdx.x;
    int e = -1, tile = 0, count = 0;
    int acc = 0;
    #pragma unroll
    for (int k = 0; k < NEXP; ++k) {
        int c = counts[k]; if (c > CAP) c = CAP;
        int t = (c + MT - 1) >> 6;              // ceil(c / 64)
        if (e < 0 && bid < acc + t) { e = k; tile = bid - acc; count = c; }
        acc += t;
    }
    if (e < 0) return;                           // beyond total real tiles
    int base = tile * MT;
    int mvalid = count - base; if (mvalid > MT) mvalid = MT;

    __shared__ ushort_t wbuf[2][STEP_SHORTS];   // 36 KB

    int tid = threadIdx.x;
    int lane = tid & 63;
    int w = tid >> 6;
    int l15 = lane & 15;
    int quad = lane >> 4;

    const int* listE = lists + (size_t)e * CAP + base;
    const ushort_t* wiPe = wiP + (size_t)e * 32 * 5 * 64 * 8;
    const ushort_t* woPe = woP + (size_t)e * 8 * 16 * 64 * 8;

    // kick off step-0 weight staging before the x gather (overlap L2 latency)
    stage_step(wiPe, woPe, wbuf[0], 0, tid);

    // ---- x B-fragment in registers: lane holds x[k=s*32+quad*8+j][tok=base+w*16+l15]
    bf16x8 xf[5];
    int row = w * 16 + l15;
    int tok = -1, bi = 0;
    if (row < mvalid) { tok = listE[row]; bi = bindex[tok]; }
    #pragma unroll
    for (int s = 0; s < 5; ++s)
        xf[s] = load_x8(hidden, emb, tok, bi, s * 32 + quad * 8);

    f32x4 yacc[8] = {};

    #pragma unroll 2
    for (int step = 0; step < 16; ++step) {     // 16 K-steps of 32 hidden units
        int cur = step & 1;
        __syncthreads();                        // wbuf[cur] staged (drains vmcnt)
        if (step + 1 < 16)
            stage_step(wiPe, woPe, wbuf[cur ^ 1], step + 1, tid);

        const ushort_t* wiS = wbuf[cur];            // [2 tiles][5 s][64][8]
        const ushort_t* woS = wbuf[cur] + 5120;     // [8 n][64][8]

        // GEMM1^T: hT[32 hid x 16 tok] = Wi-tiles @ x  (hid order permuted)
        f32x4 hacc[2] = {};
        #pragma unroll
        for (int s = 0; s < 5; ++s) {
            bf16x8 a0 = *(const bf16x8*)&wiS[(0 * 5 + s) * 512 + lane * 8];
            bf16x8 a1 = *(const bf16x8*)&wiS[(1 * 5 + s) * 512 + lane * 8];
            hacc[0] = __builtin_amdgcn_mfma_f32_16x16x32_bf16(a0, xf[s], hacc[0], 0, 0, 0);
            hacc[1] = __builtin_amdgcn_mfma_f32_16x16x32_bf16(a1, xf[s], hacc[1], 0, 0, 0);
        }
        // relu + pack: lane-local A-frag build (hidden-permutation => no shuffles)
        f32x4 h0 = hacc[0], h1 = hacc[1];
        #pragma unroll
        for (int r = 0; r < 4; ++r) {
            h0[r] = h0[r] > 0.f ? h0[r] : 0.f;
            h1[r] = h1[r] > 0.f ? h1[r] : 0.f;
        }
        uint4 dv = { pk2(h0[0], h0[1]), pk2(h0[2], h0[3]),
                     pk2(h1[0], h1[1]), pk2(h1[2], h1[3]) };
        bf16x8 afrag = __builtin_bit_cast(bf16x8, dv);

        // GEMM2: b-frag from LDS, one MFMA per n
        #pragma unroll
        for (int n = 0; n < 8; ++n) {
            bf16x8 b = *(const bf16x8*)&woS[(n * 64 + lane) * 8];
            yacc[n] = __builtin_amdgcn_mfma_f32_16x16x32_bf16(afrag, b, yacc[n], 0, 0, 0);
        }
    }

    // epilogue: yacc C-layout -> out[token][dmodel]
    #pragma unroll
    for (int r = 0; r < 4; ++r) {
        int orow = w * 16 + quad * 4 + r;
        if (orow < mvalid) {
            int t = listE[orow];
            float* dst = out + (size_t)t * DMODEL + l15;
            #pragma unroll
            for (int n = 0; n < 8; ++n)
                dst[n * 16] = yacc[n][r];
        }
    }
}

extern "C" void kernel_launch(void* const* d_in, const int* in_sizes, int n_in,
                              void* d_out, int out_size, void* d_ws, size_t ws_size,
                              hipStream_t stream) {
    const float* hidden = (const float*)d_in[0];
    const int*   pos    = (const int*)d_in[1];
    const int*   beh    = (const int*)d_in[2];
    const float* Wi     = (const float*)d_in[3];
    const float* Wo     = (const float*)d_in[4];
    const float* emb    = (const float*)d_in[5];

    char* ws = (char*)d_ws;
    int* counts   = (int*)(ws + OFF_COUNTS);
    int* lists    = (int*)(ws + OFF_LISTS);
    ushort_t* wiP = (ushort_t*)(ws + OFF_WIP);
    ushort_t* woP = (ushort_t*)(ws + OFF_WOP);

    hipMemsetAsync(counts, 0, NEXP * sizeof(int), stream);
    prep_kernel<<<SCATTER_BLOCKS + PACK_BLOCKS, 256, 0, stream>>>(pos, counts, lists, Wi, Wo, wiP, woP);
    expert_gemm<<<GEMM_BLOCKS, 256, 0, stream>>>(
        hidden, beh, lists, counts, wiP, woP, emb, (float*)d_out);
}